// Round 8
// baseline (580.543 us; speedup 1.0000x reference)
//
#include <hip/hip_runtime.h>
#include <cstdint>
#include <cstddef>

#define BN_EPS 1e-5

// ---------------- reductions (fp64 for exact sign decisions) ----------------

__global__ void zero_d(double* p, int n) {
  int i = blockIdx.x * blockDim.x + threadIdx.x;
  if (i < n) p[i] = 0.0;
}

// one contiguous HW plane per block: grid (C, N)
__global__ void reduce_plane(const float* __restrict__ x, double* __restrict__ sums,
                             int C, int HW) {
  int c = blockIdx.x, n = blockIdx.y;
  const float* p = x + ((long)n * C + c) * HW;
  double s = 0.0, s2 = 0.0;
  for (int i = threadIdx.x; i < HW; i += blockDim.x) {
    double v = (double)p[i];
    s += v; s2 += v * v;
  }
  for (int o = 32; o > 0; o >>= 1) {
    s  += __shfl_down(s, o, 64);
    s2 += __shfl_down(s2, o, 64);
  }
  __shared__ double ls[4], ls2[4];
  int lane = threadIdx.x & 63, w = threadIdx.x >> 6;
  if (lane == 0) { ls[w] = s; ls2[w] = s2; }
  __syncthreads();
  if (threadIdx.x == 0) {
    double a = 0, b = 0;
    for (int i = 0; i < 4; i++) { a += ls[i]; b += ls2[i]; }
    atomicAdd(&sums[2 * c], a);
    atomicAdd(&sums[2 * c + 1], b);
  }
}

// channel-last fp32 reduce: x [rows][C]; grid (C/64, RB)
__global__ void reduce_cl(const float* __restrict__ x, double* __restrict__ sums,
                          int C, long rows) {
  int lane = threadIdx.x & 63, wv = threadIdx.x >> 6;
  int c = blockIdx.x * 64 + lane;
  double s = 0.0, s2 = 0.0;
  for (long r = blockIdx.y * 4 + wv; r < rows; r += (long)gridDim.y * 4) {
    double v = (double)x[r * C + c];
    s += v; s2 += v * v;
  }
  __shared__ double ls[4][64], ls2[4][64];
  ls[wv][lane] = s; ls2[wv][lane] = s2;
  __syncthreads();
  if (threadIdx.x < 64) {
    double a = ls[0][lane] + ls[1][lane] + ls[2][lane] + ls[3][lane];
    double b = ls2[0][lane] + ls2[1][lane] + ls2[2][lane] + ls2[3][lane];
    atomicAdd(&sums[2 * c], a);
    atomicAdd(&sums[2 * c + 1], b);
  }
}

// row-split per-feature reduce of R x F (F % 256 == 0); grid (F/256, RB)
__global__ void reduce_cols2(const float* __restrict__ x, double* __restrict__ sums,
                             int R, int F, int RS) {
  int f = blockIdx.x * blockDim.x + threadIdx.x;
  int r0 = blockIdx.y * RS, r1 = min(r0 + RS, R);
  double s = 0.0, s2 = 0.0;
  for (int r = r0; r < r1; r++) {
    double v = (double)x[(long)r * F + f];
    s += v; s2 += v * v;
  }
  atomicAdd(&sums[2 * f], s);
  atomicAdd(&sums[2 * f + 1], s2);
}

__global__ void finalize_stats(const double* __restrict__ sums, double2* __restrict__ st,
                               int C, double cnt) {
  int c = blockIdx.x * blockDim.x + threadIdx.x;
  if (c >= C) return;
  double m = sums[2 * c] / cnt;
  double v = sums[2 * c + 1] / cnt - m * m;
  st[c] = make_double2(m, 1.0 / sqrt(v + BN_EPS));
}

// ---------------- int8 a1 path (a1 = raw conv1 dots in [-27,27]) ----------------

// exact integer stats: P=sum(d>0), N=sum(d<0), Qp=sum d^2 (d>0), Qn=sum d^2 (d<0)
__global__ void reduce_a1_i8(const int8_t* __restrict__ a1, int* __restrict__ isums) {
  __shared__ int ls[128][4];
  int t = threadIdx.x;
  if (t < 128) { ls[t][0] = 0; ls[t][1] = 0; ls[t][2] = 0; ls[t][3] = 0; }
  __syncthreads();
  int c4 = (t & 31) * 4, slot = t >> 5;
  int P[4] = {0, 0, 0, 0}, N[4] = {0, 0, 0, 0}, Qp[4] = {0, 0, 0, 0}, Qn[4] = {0, 0, 0, 0};
  for (long r = (long)blockIdx.x * 8 + slot; r < 123008; r += (long)gridDim.x * 8) {
    uint32_t u = *(const uint32_t*)(a1 + r * 128 + c4);
#pragma unroll
    for (int k = 0; k < 4; k++) {
      int d = (int)(int8_t)(u >> (8 * k));
      int dp = max(d, 0), dn = min(d, 0);
      P[k] += dp; N[k] += dn;
      Qp[k] += dp * dp; Qn[k] += dn * dn;
    }
  }
#pragma unroll
  for (int k = 0; k < 4; k++) {
    int c = c4 + k;
    atomicAdd(&ls[c][0], P[k]);  atomicAdd(&ls[c][1], N[k]);
    atomicAdd(&ls[c][2], Qp[k]); atomicAdd(&ls[c][3], Qn[k]);
  }
  __syncthreads();
  if (t < 128) {
    atomicAdd(&isums[4 * t + 0], ls[t][0]);
    atomicAdd(&isums[4 * t + 1], ls[t][1]);
    atomicAdd(&isums[4 * t + 2], ls[t][2]);
    atomicAdd(&isums[4 * t + 3], ls[t][3]);
  }
}

// prelu(d) = d>=0 ? d : alpha*d ; sums/sumsq via exact dyadic alpha algebra
__global__ void finalize_i8(const int* __restrict__ isums, const float* __restrict__ ap,
                            double2* __restrict__ st, double cnt) {
  int c = threadIdx.x;
  double a = (double)ap[0];
  double sum = (double)isums[4 * c] + a * (double)isums[4 * c + 1];
  double sq  = (double)isums[4 * c + 2] + a * a * (double)isums[4 * c + 3];
  double m = sum / cnt;
  double v = sq / cnt - m * m;
  st[c] = make_double2(m, 1.0 / sqrt(v + BN_EPS));
}

// a1 int8 [row][128] -> packed sign bits [row][2]; prelu+BN inline
__global__ void pack_a1_i8(const int8_t* __restrict__ a1, const double2* __restrict__ st,
                           const float* __restrict__ g, const float* __restrict__ b,
                           const float* __restrict__ ap, uint64_t* __restrict__ out) {
  long wid = (long)blockIdx.x * 4 + (threadIdx.x >> 6);
  if (wid >= 246016L) return;
  int lane = threadIdx.x & 63;
  long row = wid >> 1;
  int c = (int)((wid & 1) * 64 + lane);
  float alpha = ap[0];
  int d = (int)a1[row * 128 + c];
  float v = d >= 0 ? (float)d : alpha * (float)d;
  double2 s = st[c];
  float xn = (float)(((double)v - s.x) * s.y) * g[c] + b[c];
  uint64_t m = __ballot(xn > 0.f);
  if (lane == 0) out[wid] = m;
}

// ---------------- ballot-based sign/pack kernels ----------------

__global__ void pack_bits_c1(const float* __restrict__ x, const double2* __restrict__ st,
                             const float* __restrict__ g, const float* __restrict__ b,
                             uint64_t* __restrict__ rows) {
  int wid = blockIdx.x * 4 + (threadIdx.x >> 6);
  int lane = threadIdx.x & 63;
  int n = wid / 192, rem = wid % 192;
  int ci = rem >> 6, y = rem & 63;
  double2 s = st[ci];
  float xv = x[(((long)n * 3 + ci) * 64 + y) * 64 + lane];
  float xn = (float)(((double)xv - s.x) * s.y) * g[ci] + b[ci];
  uint64_t m = __ballot(xn > 0.f);
  if (lane == 0) rows[wid] = m;
}

__global__ void pack_wc1(const float* __restrict__ w, uint32_t* __restrict__ wm) {
  int co = threadIdx.x;
  uint32_t m = 0;
  for (int j = 0; j < 27; j++) m |= (uint32_t)(w[co * 27 + j] > 0.f) << j;
  wm[co] = m;
}

__global__ void pack_cl(const float* __restrict__ acl, const double2* __restrict__ st,
                        const float* __restrict__ g, const float* __restrict__ b,
                        uint64_t* __restrict__ out, int C, long nwords, int lw) {
  long wid = (long)blockIdx.x * 4 + (threadIdx.x >> 6);
  if (wid >= nwords) return;
  int lane = threadIdx.x & 63;
  long row = wid >> lw;
  int w = (int)(wid & ((1 << lw) - 1));
  int c = w * 64 + lane;
  double2 s = st[c];
  float xv = acl[row * C + c];
  float xn = (float)(((double)xv - s.x) * s.y) * g[c] + b[c];
  uint64_t m = __ballot(xn > 0.f);
  if (lane == 0) out[wid] = m;
}

__global__ void pack_wconv(const float* __restrict__ w, uint64_t* __restrict__ out,
                           int CO, int CI, int W) {
  int i = blockIdx.x * blockDim.x + threadIdx.x;
  int total = CO * 9 * W;
  if (i >= total) return;
  int wd = i % W;
  int t = i / W;
  int tap = t % 9, co = t / 9;
  uint64_t bits = 0;
  for (int k = 0; k < 64; k++) {
    int ci = wd * 64 + k;
    bits |= (uint64_t)(w[((long)co * CI + ci) * 9 + tap] > 0.f) << k;
  }
  out[i] = bits;
}

__global__ void pack_nz(const float* __restrict__ x, const double2* __restrict__ st,
                        const float* __restrict__ g, const float* __restrict__ b,
                        uint64_t* __restrict__ out, int R, int F) {
  int Wf = F >> 6;
  long wid = (long)blockIdx.x * 4 + (threadIdx.x >> 6);
  if (wid >= (long)R * Wf) return;
  int lane = threadIdx.x & 63;
  long r = wid / Wf;
  int w = (int)(wid % Wf);
  int f = w * 64 + lane;
  double2 s = st[f];
  double d = (double)x[r * F + f] - s.x;  // exact for lattice values
  float xn = (float)(d * s.y) * g[f] + b[f];
  uint64_t sm = __ballot(xn > 0.f);
  uint64_t nm = __ballot(d != 0.0);
  if (lane == 0) { out[2 * wid] = sm; out[2 * wid + 1] = nm; }
}

__global__ void pack_wfc2(const float* __restrict__ w, uint64_t* __restrict__ out,
                          int O, int F) {
  int Wf = F >> 6;
  long wid = (long)blockIdx.x * 4 + (threadIdx.x >> 6);
  if (wid >= (long)O * Wf) return;
  int lane = threadIdx.x & 63;
  long o = wid / Wf;
  int wd = (int)(wid % Wf);
  uint64_t m = __ballot(w[o * F + wd * 64 + lane] > 0.f);
  if (lane == 0) out[wid] = m;
}

// ---------------- fused conv + maxpool ----------------

// conv1 via 27-bit xnor-popcount; OUT = RAW INT8 DOT (prelu deferred to reduce/pack)
__global__ __launch_bounds__(256) void conv1_pool3(const uint64_t* __restrict__ rows,
                                                   const uint32_t* __restrict__ wm,
                                                   int8_t* __restrict__ out) {
  __shared__ uint64_t rL[192];
  __shared__ uint32_t wL[128];
  __shared__ uint32_t mL[61 * 4];
  int n = blockIdx.y, chunk = blockIdx.x, t = threadIdx.x;
  if (t < 192) rL[t] = rows[n * 192 + t];
  if (t < 128) wL[t] = wm[t];
  __syncthreads();
  if (t < 244) {
    int pl = t >> 2, quad = t & 3;
    int pos = chunk * 61 + pl;
    if (pos < 961) {
      int py = pos / 31, px = pos - py * 31;
      int cy = 2 * py + (quad >> 1), cx = 2 * px + (quad & 1);
      uint32_t m = 0;
#pragma unroll
      for (int ci = 0; ci < 3; ci++)
#pragma unroll
        for (int ky = 0; ky < 3; ky++)
          m |= (uint32_t)((rL[ci * 64 + cy + ky] >> cx) & 7) << (ci * 9 + ky * 3);
      mL[pl * 4 + quad] = m;
    }
  }
  __syncthreads();
  int co = t & 127, slot = t >> 7;
  uint32_t w = wL[co];
  for (int i = slot; i < 61; i += 2) {
    int pos = chunk * 61 + i;
    if (pos >= 961) break;
    int p0 = __popc(mL[4 * i] ^ w);
    int p1 = __popc(mL[4 * i + 1] ^ w);
    int p2 = __popc(mL[4 * i + 2] ^ w);
    int p3 = __popc(mL[4 * i + 3] ^ w);
    int dot = 27 - 2 * min(min(p0, p1), min(p2, p3));
    out[((long)n * 961 + pos) * 128 + co] = (int8_t)dot;
  }
}

// half-window load: columns (cx, cx+1), rows cy=0..3; values PINNED in VGPRs via
// empty asm so the scheduler cannot sink/rematerialize the LDS reads.
template <int W, int IH>
__device__ __forceinline__ void load_half(uint64_t (&h)[4][2 * W],
                                          const uint64_t* __restrict__ sIn,
                                          int py, int cx) {
#pragma unroll
  for (int cy = 0; cy < 4; cy++) {
    const uint64_t* p = &sIn[((2 * py + cy) * IH + cx) * W];
#pragma unroll
    for (int i = 0; i < 2 * W; i++) {
      h[cy][i] = p[i];
      asm volatile("" : "+v"(h[cy][i]));
    }
  }
}

template <int W>
__device__ __forceinline__ void conv_quad(const uint64_t (&A)[4][2 * W],
                                          const uint64_t (&B)[4][2 * W],
                                          const uint64_t (&wr)[9 * W],
                                          int& a00, int& a01, int& a10, int& a11) {
  a00 = a01 = a10 = a11 = 0;
#pragma unroll
  for (int cy = 0; cy < 4; cy++) {
#pragma unroll
    for (int dy = 0; dy < 2; dy++) {
      int ky = cy - dy;
      if (ky < 0 || ky > 2) continue;  // compile-time folded
#pragma unroll
      for (int dx = 0; dx < 2; dx++) {
        int acc = 0;
#pragma unroll
        for (int kx = 0; kx < 3; kx++) {
          int col = dx + kx;
#pragma unroll
          for (int wd = 0; wd < W; wd++) {
            uint64_t pv = (col < 2) ? A[cy][col * W + wd] : B[cy][(col - 2) * W + wd];
            acc += __popcll(pv ^ wr[(ky * 3 + kx) * W + wd]);
          }
        }
        if (dy == 0) { if (dx == 0) a00 += acc; else a01 += acc; }
        else         { if (dx == 0) a10 += acc; else a11 += acc; }
      }
    }
  }
}

// sliding-window xnor conv + pool + prelu. wr pinned in VGPRs (asm) so weight
// loads cannot sink into the loop; px loop NOT unrolled (R7's full unroll blew
// the scheduler's pressure heuristic -> it rematerialized everything).
template <int W, int IH, int PH, int CHUNK, bool CL>
__global__ __launch_bounds__(256, 2) void convp_slide(
    const uint64_t* __restrict__ in, const uint64_t* __restrict__ wt,
    const float* __restrict__ cp, float* __restrict__ out, int CO) {
  __shared__ uint64_t sIn[IH * IH * W];
  int n = blockIdx.y;
  int cg = blockIdx.x / CHUNK, chunk = blockIdx.x % CHUNK;
  int t = threadIdx.x, lane = t & 63, slot = t >> 6;
  const uint64_t* src = in + (long)n * (IH * IH * W);
  for (int i = t; i < IH * IH * W; i += 256) sIn[i] = src[i];
  int co = cg * 64 + lane;
  uint64_t wr[9 * W];
  const uint64_t* wg = wt + (long)co * (9 * W);
#pragma unroll
  for (int i = 0; i < 9 * W; i++) {
    wr[i] = wg[i];
    asm volatile("" : "+v"(wr[i]));
  }
  __syncthreads();
  int py = chunk * 4 + slot;
  if (py >= PH) return;
  float alpha = cp[0];
  const int K = 9 * 64 * W;
  uint64_t hA[4][2 * W], hB[4][2 * W];
  load_half<W, IH>(hA, sIn, py, 0);
#pragma unroll 1
  for (int px = 0; px < PH; px += 2) {
    load_half<W, IH>(hB, sIn, py, 2 * px + 2);
    {
      int a00, a01, a10, a11;
      conv_quad<W>(hA, hB, wr, a00, a01, a10, a11);
      int dot = K - 2 * min(min(a00, a01), min(a10, a11));
      float f = (float)dot;
      long idx = CL ? (((long)n * PH * PH + py * PH + px) * CO + co)
                    : (((long)n * CO + co) * PH * PH + py * PH + px);
      out[idx] = dot >= 0 ? f : alpha * f;
    }
    if (px + 1 < PH) {
      load_half<W, IH>(hA, sIn, py, 2 * px + 4);
      int a00, a01, a10, a11;
      conv_quad<W>(hB, hA, wr, a00, a01, a10, a11);
      int dot = K - 2 * min(min(a00, a01), min(a10, a11));
      float f = (float)dot;
      long idx = CL ? (((long)n * PH * PH + py * PH + px + 1) * CO + co)
                    : (((long)n * CO + co) * PH * PH + py * PH + px + 1);
      out[idx] = dot >= 0 ? f : alpha * f;
    }
  }
}

// ---------------- binary fc (with nonzero mask on activations) ----------------

__global__ void fc_bin(const uint64_t* __restrict__ xp, const uint64_t* __restrict__ wp,
                       const float* __restrict__ cp, float* __restrict__ out,
                       int O, int Wf) {
  __shared__ uint64_t xs[288], xz[288];
  int r = blockIdx.y;
  for (int i = threadIdx.x; i < Wf; i += blockDim.x) {
    xs[i] = xp[((long)r * Wf + i) * 2];
    xz[i] = xp[((long)r * Wf + i) * 2 + 1];
  }
  __syncthreads();
  int o = blockIdx.x * blockDim.x + threadIdx.x;
  if (o >= O) return;
  int pc = 0, nzc = 0;
  const uint64_t* wr = wp + (long)o * Wf;
  for (int wd = 0; wd < Wf; wd++) {
    uint64_t nz = xz[wd];
    pc  += __popcll((xs[wd] ^ wr[wd]) & nz);
    nzc += __popcll(nz);
  }
  int dot = nzc - 2 * pc;
  float f = (float)dot;
  float alpha = cp[0];
  out[(long)r * O + o] = dot >= 0 ? f : alpha * f;
}

__global__ void fc_bin_scale(const uint64_t* __restrict__ xp, const uint64_t* __restrict__ wp,
                             const float* __restrict__ cp, const float* __restrict__ scale,
                             float* __restrict__ out, int R, int O, int Wf) {
  int i = blockIdx.x * blockDim.x + threadIdx.x;
  if (i >= R * O) return;
  int o = i % O, r = i / O;
  int pc = 0, nzc = 0;
  for (int wd = 0; wd < Wf; wd++) {
    uint64_t nz = xp[((long)r * Wf + wd) * 2 + 1];
    pc  += __popcll((xp[((long)r * Wf + wd) * 2] ^ wp[(long)o * Wf + wd]) & nz);
    nzc += __popcll(nz);
  }
  int dot = nzc - 2 * pc;
  float f = (float)dot;
  float alpha = cp[0];
  f = dot >= 0 ? f : alpha * f;
  out[i] = f * scale[0];
}

// ---------------- launch ----------------

extern "C" void kernel_launch(void* const* d_in, const int* in_sizes, int n_in,
                              void* d_out, int out_size, void* d_ws, size_t ws_size,
                              hipStream_t stream) {
  const float* x   = (const float*)d_in[0];
  const float* cg0 = (const float*)d_in[1];
  const float* cb0 = (const float*)d_in[2];
  const float* cw0 = (const float*)d_in[3];
  const float* cp0 = (const float*)d_in[4];
  const float* cg1 = (const float*)d_in[5];
  const float* cb1 = (const float*)d_in[6];
  const float* cw1 = (const float*)d_in[7];
  const float* cp1 = (const float*)d_in[8];
  const float* cg2 = (const float*)d_in[9];
  const float* cb2 = (const float*)d_in[10];
  const float* cw2 = (const float*)d_in[11];
  const float* cp2 = (const float*)d_in[12];
  const float* fg0 = (const float*)d_in[13];
  const float* fb0 = (const float*)d_in[14];
  const float* fw0 = (const float*)d_in[15];
  const float* fp0 = (const float*)d_in[16];
  const float* fg1 = (const float*)d_in[17];
  const float* fb1 = (const float*)d_in[18];
  const float* fw1 = (const float*)d_in[19];
  const float* fp1 = (const float*)d_in[20];
  const float* scl = (const float*)d_in[21];

  char* ws = (char*)d_ws;
  size_t off = 0;
  auto alloc = [&](size_t bytes) {
    size_t r = off;
    off += (bytes + 255) & ~(size_t)255;
    return r;
  };
  const int C0_OFF = 0, C1_OFF = 16, C2_OFF = 160, C3_OFF = 448, C4_OFF = 18944;
  const int NCH = 19968;

  double*   sums  = (double*)(ws + alloc(((size_t)NCH * 2 + 256) * sizeof(double)));
  int*      isums = (int*)(sums + (size_t)NCH * 2);  // 512 int32 for a1 int stats
  double2*  stats = (double2*)(ws + alloc((size_t)NCH * sizeof(double2)));
  uint64_t* rows0 = (uint64_t*)(ws + alloc(128L * 3 * 64 * 8));
  uint32_t* wm1   = (uint32_t*)(ws + alloc(128L * 4));
  int8_t*   a1    = (int8_t*)(ws + alloc(128L * 961 * 128));      // int8 raw dots, channel-last
  uint64_t* s1p   = (uint64_t*)(ws + alloc(128L * 961 * 2 * 8));
  uint64_t* w1p   = (uint64_t*)(ws + alloc(256L * 9 * 2 * 8));
  float*    a2    = (float*)(ws + alloc(128L * 196 * 256 * 4));   // channel-last
  uint64_t* s2p   = (uint64_t*)(ws + alloc(128L * 196 * 4 * 8));
  uint64_t* w2p   = (uint64_t*)(ws + alloc(512L * 9 * 4 * 8));
  float*    a3    = (float*)(ws + alloc(128L * 512 * 36 * 4));    // channel-major (reshape order)
  uint64_t* s3p   = (uint64_t*)(ws + alloc(128L * 288 * 2 * 8));
  uint64_t* w3p   = (uint64_t*)(ws + alloc(1024L * 288 * 8));
  float*    f1    = (float*)(ws + alloc(128L * 1024 * 4));
  uint64_t* s4p   = (uint64_t*)(ws + alloc(128L * 16 * 2 * 8));
  uint64_t* w4p   = (uint64_t*)(ws + alloc(10L * 16 * 8));

  const int B = 256;

  zero_d<<<dim3(157), B, 0, stream>>>(sums, NCH * 2 + 256);  // fp64 sums + isums

  // ---- block 0: BN(x) -> sign-bits -> conv1(popcount) -> pool (raw int8 dots) ----
  reduce_plane<<<dim3(3, 128), B, 0, stream>>>(x, sums + 2 * C0_OFF, 3, 4096);
  finalize_stats<<<1, 64, 0, stream>>>(sums + 2 * C0_OFF, stats + C0_OFF, 3, 524288.0);
  pack_bits_c1<<<dim3(6144), B, 0, stream>>>(x, stats + C0_OFF, cg0, cb0, rows0);
  pack_wc1<<<1, 128, 0, stream>>>(cw0, wm1);
  conv1_pool3<<<dim3(16, 128), B, 0, stream>>>(rows0, wm1, a1);

  // ---- block 1: int-stat BN(a1) -> pack(prelu inline) -> conv2 -> pool -> prelu ----
  reduce_a1_i8<<<dim3(768), B, 0, stream>>>(a1, isums);
  finalize_i8<<<1, 128, 0, stream>>>(isums, cp0, stats + C1_OFF, 123008.0);
  pack_a1_i8<<<dim3(61504), B, 0, stream>>>(a1, stats + C1_OFF, cg1, cb1, cp0, s1p);
  pack_wconv<<<dim3(18), B, 0, stream>>>(cw1, w1p, 256, 128, 2);
  convp_slide<2, 31, 14, 4, true><<<dim3(16, 128), B, 0, stream>>>(s1p, w1p, cp1, a2, 256);

  // ---- block 2: BN(a2) -> pack -> conv3 -> pool -> prelu ----
  reduce_cl<<<dim3(4, 128), B, 0, stream>>>(a2, sums + 2 * C2_OFF, 256, 25088L);
  finalize_stats<<<1, 256, 0, stream>>>(sums + 2 * C2_OFF, stats + C2_OFF, 256, 25088.0);
  pack_cl<<<dim3(25088), B, 0, stream>>>(a2, stats + C2_OFF, cg2, cb2, s2p, 256, 100352L, 2);
  pack_wconv<<<dim3(72), B, 0, stream>>>(cw2, w2p, 512, 256, 4);
  convp_slide<4, 14, 6, 2, false><<<dim3(16, 128), B, 0, stream>>>(s2p, w2p, cp2, a3, 512);

  // ---- fc 0: BN1d -> sign @ sign(W).T -> prelu ----
  reduce_cols2<<<dim3(72, 8), B, 0, stream>>>(a3, sums + 2 * C3_OFF, 128, 18432, 16);
  finalize_stats<<<dim3(72), B, 0, stream>>>(sums + 2 * C3_OFF, stats + C3_OFF, 18432, 128.0);
  pack_nz<<<dim3(9216), B, 0, stream>>>(a3, stats + C3_OFF, fg0, fb0, s3p, 128, 18432);
  pack_wfc2<<<dim3(73728), B, 0, stream>>>(fw0, w3p, 1024, 18432);
  fc_bin<<<dim3(4, 128), B, 0, stream>>>(s3p, w3p, fp0, f1, 1024, 288);

  // ---- fc 1: BN1d -> sign @ sign(W).T -> prelu -> scale ----
  reduce_cols2<<<dim3(4, 8), B, 0, stream>>>(f1, sums + 2 * C4_OFF, 128, 1024, 16);
  finalize_stats<<<dim3(4), B, 0, stream>>>(sums + 2 * C4_OFF, stats + C4_OFF, 1024, 128.0);
  pack_nz<<<dim3(512), B, 0, stream>>>(f1, stats + C4_OFF, fg1, fb1, s4p, 128, 1024);
  pack_wfc2<<<dim3(40), B, 0, stream>>>(fw1, w4p, 10, 1024);
  fc_bin_scale<<<dim3(5), B, 0, stream>>>(s4p, w4p, fp1, scl, (float*)d_out, 128, 10, 16);
}

// Round 9
// 543.531 us; speedup vs baseline: 1.0681x; 1.0681x over previous
//
#include <hip/hip_runtime.h>
#include <cstdint>
#include <cstddef>

#define BN_EPS 1e-5

// ---------------- reductions (fp64 for exact sign decisions) ----------------

__global__ void zero_d(double* p, int n) {
  int i = blockIdx.x * blockDim.x + threadIdx.x;
  if (i < n) p[i] = 0.0;
}

// one contiguous HW plane per block: grid (C, N)
__global__ void reduce_plane(const float* __restrict__ x, double* __restrict__ sums,
                             int C, int HW) {
  int c = blockIdx.x, n = blockIdx.y;
  const float* p = x + ((long)n * C + c) * HW;
  double s = 0.0, s2 = 0.0;
  for (int i = threadIdx.x; i < HW; i += blockDim.x) {
    double v = (double)p[i];
    s += v; s2 += v * v;
  }
  for (int o = 32; o > 0; o >>= 1) {
    s  += __shfl_down(s, o, 64);
    s2 += __shfl_down(s2, o, 64);
  }
  __shared__ double ls[4], ls2[4];
  int lane = threadIdx.x & 63, w = threadIdx.x >> 6;
  if (lane == 0) { ls[w] = s; ls2[w] = s2; }
  __syncthreads();
  if (threadIdx.x == 0) {
    double a = 0, b = 0;
    for (int i = 0; i < 4; i++) { a += ls[i]; b += ls2[i]; }
    atomicAdd(&sums[2 * c], a);
    atomicAdd(&sums[2 * c + 1], b);
  }
}

// channel-last fp32 reduce: x [rows][C]; grid (C/64, RB)
__global__ void reduce_cl(const float* __restrict__ x, double* __restrict__ sums,
                          int C, long rows) {
  int lane = threadIdx.x & 63, wv = threadIdx.x >> 6;
  int c = blockIdx.x * 64 + lane;
  double s = 0.0, s2 = 0.0;
  for (long r = blockIdx.y * 4 + wv; r < rows; r += (long)gridDim.y * 4) {
    double v = (double)x[r * C + c];
    s += v; s2 += v * v;
  }
  __shared__ double ls[4][64], ls2[4][64];
  ls[wv][lane] = s; ls2[wv][lane] = s2;
  __syncthreads();
  if (threadIdx.x < 64) {
    double a = ls[0][lane] + ls[1][lane] + ls[2][lane] + ls[3][lane];
    double b = ls2[0][lane] + ls2[1][lane] + ls2[2][lane] + ls2[3][lane];
    atomicAdd(&sums[2 * c], a);
    atomicAdd(&sums[2 * c + 1], b);
  }
}

// row-split per-feature reduce of R x F (F % 256 == 0); grid (F/256, RB)
__global__ void reduce_cols2(const float* __restrict__ x, double* __restrict__ sums,
                             int R, int F, int RS) {
  int f = blockIdx.x * blockDim.x + threadIdx.x;
  int r0 = blockIdx.y * RS, r1 = min(r0 + RS, R);
  double s = 0.0, s2 = 0.0;
  for (int r = r0; r < r1; r++) {
    double v = (double)x[(long)r * F + f];
    s += v; s2 += v * v;
  }
  atomicAdd(&sums[2 * f], s);
  atomicAdd(&sums[2 * f + 1], s2);
}

__global__ void finalize_stats(const double* __restrict__ sums, double2* __restrict__ st,
                               int C, double cnt) {
  int c = blockIdx.x * blockDim.x + threadIdx.x;
  if (c >= C) return;
  double m = sums[2 * c] / cnt;
  double v = sums[2 * c + 1] / cnt - m * m;
  st[c] = make_double2(m, 1.0 / sqrt(v + BN_EPS));
}

// ---------------- int8 a1 path (a1 = raw conv1 dots in [-27,27]) ----------------

__global__ void reduce_a1_i8(const int8_t* __restrict__ a1, int* __restrict__ isums) {
  __shared__ int ls[128][4];
  int t = threadIdx.x;
  if (t < 128) { ls[t][0] = 0; ls[t][1] = 0; ls[t][2] = 0; ls[t][3] = 0; }
  __syncthreads();
  int c4 = (t & 31) * 4, slot = t >> 5;
  int P[4] = {0, 0, 0, 0}, N[4] = {0, 0, 0, 0}, Qp[4] = {0, 0, 0, 0}, Qn[4] = {0, 0, 0, 0};
  for (long r = (long)blockIdx.x * 8 + slot; r < 123008; r += (long)gridDim.x * 8) {
    uint32_t u = *(const uint32_t*)(a1 + r * 128 + c4);
#pragma unroll
    for (int k = 0; k < 4; k++) {
      int d = (int)(int8_t)(u >> (8 * k));
      int dp = max(d, 0), dn = min(d, 0);
      P[k] += dp; N[k] += dn;
      Qp[k] += dp * dp; Qn[k] += dn * dn;
    }
  }
#pragma unroll
  for (int k = 0; k < 4; k++) {
    int c = c4 + k;
    atomicAdd(&ls[c][0], P[k]);  atomicAdd(&ls[c][1], N[k]);
    atomicAdd(&ls[c][2], Qp[k]); atomicAdd(&ls[c][3], Qn[k]);
  }
  __syncthreads();
  if (t < 128) {
    atomicAdd(&isums[4 * t + 0], ls[t][0]);
    atomicAdd(&isums[4 * t + 1], ls[t][1]);
    atomicAdd(&isums[4 * t + 2], ls[t][2]);
    atomicAdd(&isums[4 * t + 3], ls[t][3]);
  }
}

__global__ void finalize_i8(const int* __restrict__ isums, const float* __restrict__ ap,
                            double2* __restrict__ st, double cnt) {
  int c = threadIdx.x;
  double a = (double)ap[0];
  double sum = (double)isums[4 * c] + a * (double)isums[4 * c + 1];
  double sq  = (double)isums[4 * c + 2] + a * a * (double)isums[4 * c + 3];
  double m = sum / cnt;
  double v = sq / cnt - m * m;
  st[c] = make_double2(m, 1.0 / sqrt(v + BN_EPS));
}

__global__ void pack_a1_i8(const int8_t* __restrict__ a1, const double2* __restrict__ st,
                           const float* __restrict__ g, const float* __restrict__ b,
                           const float* __restrict__ ap, uint64_t* __restrict__ out) {
  long wid = (long)blockIdx.x * 4 + (threadIdx.x >> 6);
  if (wid >= 246016L) return;
  int lane = threadIdx.x & 63;
  long row = wid >> 1;
  int c = (int)((wid & 1) * 64 + lane);
  float alpha = ap[0];
  int d = (int)a1[row * 128 + c];
  float v = d >= 0 ? (float)d : alpha * (float)d;
  double2 s = st[c];
  float xn = (float)(((double)v - s.x) * s.y) * g[c] + b[c];
  uint64_t m = __ballot(xn > 0.f);
  if (lane == 0) out[wid] = m;
}

// ---------------- ballot-based sign/pack kernels ----------------

__global__ void pack_bits_c1(const float* __restrict__ x, const double2* __restrict__ st,
                             const float* __restrict__ g, const float* __restrict__ b,
                             uint64_t* __restrict__ rows) {
  int wid = blockIdx.x * 4 + (threadIdx.x >> 6);
  int lane = threadIdx.x & 63;
  int n = wid / 192, rem = wid % 192;
  int ci = rem >> 6, y = rem & 63;
  double2 s = st[ci];
  float xv = x[(((long)n * 3 + ci) * 64 + y) * 64 + lane];
  float xn = (float)(((double)xv - s.x) * s.y) * g[ci] + b[ci];
  uint64_t m = __ballot(xn > 0.f);
  if (lane == 0) rows[wid] = m;
}

__global__ void pack_wc1(const float* __restrict__ w, uint32_t* __restrict__ wm) {
  int co = threadIdx.x;
  uint32_t m = 0;
  for (int j = 0; j < 27; j++) m |= (uint32_t)(w[co * 27 + j] > 0.f) << j;
  wm[co] = m;
}

__global__ void pack_cl(const float* __restrict__ acl, const double2* __restrict__ st,
                        const float* __restrict__ g, const float* __restrict__ b,
                        uint64_t* __restrict__ out, int C, long nwords, int lw) {
  long wid = (long)blockIdx.x * 4 + (threadIdx.x >> 6);
  if (wid >= nwords) return;
  int lane = threadIdx.x & 63;
  long row = wid >> lw;
  int w = (int)(wid & ((1 << lw) - 1));
  int c = w * 64 + lane;
  double2 s = st[c];
  float xv = acl[row * C + c];
  float xn = (float)(((double)xv - s.x) * s.y) * g[c] + b[c];
  uint64_t m = __ballot(xn > 0.f);
  if (lane == 0) out[wid] = m;
}

// conv weights via LDS stage + ballot: one block per co (R8's pack_wconv was
// an 18-block strided-gather, est. 30-50us). sw: CI*9 floats (max 9.2 KB).
__global__ void pack_wconv2(const float* __restrict__ w, uint64_t* __restrict__ out,
                            int CI, int W) {
  __shared__ float sw[2304];
  int co = blockIdx.x;
  int total = CI * 9;
  const float* wc = w + (long)co * total;
  for (int i = threadIdx.x; i < total; i += blockDim.x) sw[i] = wc[i];
  __syncthreads();
  int lane = threadIdx.x & 63, wv = threadIdx.x >> 6;
  for (int word = wv; word < 9 * W; word += 4) {
    int tap = word / W, wd = word % W;  // out index = tap*W+wd (matches wr[])
    uint64_t m = __ballot(sw[(wd * 64 + lane) * 9 + tap] > 0.f);
    if (lane == 0) out[(long)co * 9 * W + word] = m;
  }
}

__global__ void pack_nz(const float* __restrict__ x, const double2* __restrict__ st,
                        const float* __restrict__ g, const float* __restrict__ b,
                        uint64_t* __restrict__ out, int R, int F) {
  int Wf = F >> 6;
  long wid = (long)blockIdx.x * 4 + (threadIdx.x >> 6);
  if (wid >= (long)R * Wf) return;
  int lane = threadIdx.x & 63;
  long r = wid / Wf;
  int w = (int)(wid % Wf);
  int f = w * 64 + lane;
  double2 s = st[f];
  double d = (double)x[r * F + f] - s.x;  // exact for lattice values
  float xn = (float)(d * s.y) * g[f] + b[f];
  uint64_t sm = __ballot(xn > 0.f);
  uint64_t nm = __ballot(d != 0.0);
  if (lane == 0) { out[2 * wid] = sm; out[2 * wid + 1] = nm; }
}

// fc weights [O][F] -> TRANSPOSED [F/64][O] so fc_bin reads are lane-coalesced
__global__ void pack_wfc2T(const float* __restrict__ w, uint64_t* __restrict__ out,
                           int O, int F) {
  int Wf = F >> 6;
  long wid = (long)blockIdx.x * 4 + (threadIdx.x >> 6);
  if (wid >= (long)O * Wf) return;
  int lane = threadIdx.x & 63;
  long o = wid / Wf;
  int wd = (int)(wid % Wf);
  uint64_t m = __ballot(w[o * F + wd * 64 + lane] > 0.f);
  if (lane == 0) out[(long)wd * O + o] = m;
}

// plain layout for the tiny final fc
__global__ void pack_wfc2(const float* __restrict__ w, uint64_t* __restrict__ out,
                          int O, int F) {
  int Wf = F >> 6;
  long wid = (long)blockIdx.x * 4 + (threadIdx.x >> 6);
  if (wid >= (long)O * Wf) return;
  int lane = threadIdx.x & 63;
  long o = wid / Wf;
  int wd = (int)(wid % Wf);
  uint64_t m = __ballot(w[o * F + wd * 64 + lane] > 0.f);
  if (lane == 0) out[wid] = m;
}

// ---------------- fused conv + maxpool ----------------

// conv1 via 27-bit xnor-popcount; OUT = RAW INT8 DOT
__global__ __launch_bounds__(256) void conv1_pool3(const uint64_t* __restrict__ rows,
                                                   const uint32_t* __restrict__ wm,
                                                   int8_t* __restrict__ out) {
  __shared__ uint64_t rL[192];
  __shared__ uint32_t wL[128];
  __shared__ uint32_t mL[61 * 4];
  int n = blockIdx.y, chunk = blockIdx.x, t = threadIdx.x;
  if (t < 192) rL[t] = rows[n * 192 + t];
  if (t < 128) wL[t] = wm[t];
  __syncthreads();
  if (t < 244) {
    int pl = t >> 2, quad = t & 3;
    int pos = chunk * 61 + pl;
    if (pos < 961) {
      int py = pos / 31, px = pos - py * 31;
      int cy = 2 * py + (quad >> 1), cx = 2 * px + (quad & 1);
      uint32_t m = 0;
#pragma unroll
      for (int ci = 0; ci < 3; ci++)
#pragma unroll
        for (int ky = 0; ky < 3; ky++)
          m |= (uint32_t)((rL[ci * 64 + cy + ky] >> cx) & 7) << (ci * 9 + ky * 3);
      mL[pl * 4 + quad] = m;
    }
  }
  __syncthreads();
  int co = t & 127, slot = t >> 7;
  uint32_t w = wL[co];
  for (int i = slot; i < 61; i += 2) {
    int pos = chunk * 61 + i;
    if (pos >= 961) break;
    int p0 = __popc(mL[4 * i] ^ w);
    int p1 = __popc(mL[4 * i + 1] ^ w);
    int p2 = __popc(mL[4 * i + 2] ^ w);
    int p3 = __popc(mL[4 * i + 3] ^ w);
    int dot = 27 - 2 * min(min(p0, p1), min(p2, p3));
    out[((long)n * 961 + pos) * 128 + co] = (int8_t)dot;
  }
}

// ---- R6-proven conv kernels, reverted verbatim (R7/R8 tweaks were -49us net) ----

template <int W, int IH>
__device__ __forceinline__ void load_half(uint64_t (&h)[4][2 * W],
                                          const uint64_t* __restrict__ sIn,
                                          int py, int cx) {
#pragma unroll
  for (int cy = 0; cy < 4; cy++) {
    const uint64_t* p = &sIn[((2 * py + cy) * IH + cx) * W];
#pragma unroll
    for (int i = 0; i < 2 * W; i++) h[cy][i] = p[i];
  }
}

template <int W>
__device__ __forceinline__ void conv_quad(const uint64_t (&A)[4][2 * W],
                                          const uint64_t (&B)[4][2 * W],
                                          const uint64_t (&wr)[9 * W],
                                          int& a00, int& a01, int& a10, int& a11) {
  a00 = a01 = a10 = a11 = 0;
#pragma unroll
  for (int cy = 0; cy < 4; cy++) {
#pragma unroll
    for (int dy = 0; dy < 2; dy++) {
      int ky = cy - dy;
      if (ky < 0 || ky > 2) continue;  // compile-time folded
#pragma unroll
      for (int dx = 0; dx < 2; dx++) {
        int acc = 0;
#pragma unroll
        for (int kx = 0; kx < 3; kx++) {
          int col = dx + kx;
#pragma unroll
          for (int wd = 0; wd < W; wd++) {
            uint64_t pv = (col < 2) ? A[cy][col * W + wd] : B[cy][(col - 2) * W + wd];
            acc += __popcll(pv ^ wr[(ky * 3 + kx) * W + wd]);
          }
        }
        if (dy == 0) { if (dx == 0) a00 += acc; else a01 += acc; }
        else         { if (dx == 0) a10 += acc; else a11 += acc; }
      }
    }
  }
}

// sliding-window conv2 (R6 form: (256,4), full unroll, channel-last out)
template <int W, int IH, int PH, int CHUNK>
__global__ __launch_bounds__(256, 4) void convp_slide(
    const uint64_t* __restrict__ in, const uint64_t* __restrict__ wt,
    const float* __restrict__ cp, float* __restrict__ out, int CO) {
  __shared__ uint64_t sIn[IH * IH * W];
  int n = blockIdx.y;
  int cg = blockIdx.x / CHUNK, chunk = blockIdx.x % CHUNK;
  int t = threadIdx.x, lane = t & 63, slot = t >> 6;
  const uint64_t* src = in + (long)n * (IH * IH * W);
  for (int i = t; i < IH * IH * W; i += 256) sIn[i] = src[i];
  int co = cg * 64 + lane;
  uint64_t wr[9 * W];
  const uint64_t* wg = wt + (long)co * (9 * W);
#pragma unroll
  for (int i = 0; i < 9 * W; i++) wr[i] = wg[i];
  __syncthreads();
  int py = chunk * 4 + slot;
  if (py >= PH) return;
  float alpha = cp[0];
  const int K = 9 * 64 * W;
  uint64_t hA[4][2 * W], hB[4][2 * W];
  load_half<W, IH>(hA, sIn, py, 0);
#pragma unroll
  for (int px = 0; px < PH; px += 2) {
    load_half<W, IH>(hB, sIn, py, 2 * px + 2);
    {
      int a00, a01, a10, a11;
      conv_quad<W>(hA, hB, wr, a00, a01, a10, a11);
      int dot = K - 2 * min(min(a00, a01), min(a10, a11));
      float f = (float)dot;
      out[((long)n * PH * PH + py * PH + px) * CO + co] = dot >= 0 ? f : alpha * f;
    }
    if (px + 1 < PH) {
      load_half<W, IH>(hA, sIn, py, 2 * px + 4);
      int a00, a01, a10, a11;
      conv_quad<W>(hB, hA, wr, a00, a01, a10, a11);
      int dot = K - 2 * min(min(a00, a01), min(a10, a11));
      float f = (float)dot;
      out[((long)n * PH * PH + py * PH + px + 1) * CO + co] = dot >= 0 ? f : alpha * f;
    }
  }
}

// per-position conv3 (R6 form: (256,4))
template <int W, int IH, int PH, int POSCH, bool CL>
__global__ __launch_bounds__(256, 4) void convp_pool3(
    const uint64_t* __restrict__ in, const uint64_t* __restrict__ wt,
    const float* __restrict__ cp, float* __restrict__ out, int CO) {
  __shared__ uint64_t sIn[IH * IH * W];
  int n = blockIdx.y;
  int cg = blockIdx.x / POSCH;
  int chunk = blockIdx.x % POSCH;
  int t = threadIdx.x;
  const uint64_t* src = in + (long)n * (IH * IH * W);
  for (int i = t; i < IH * IH * W; i += 256) sIn[i] = src[i];
  int lane = t & 63;
  int slot = t >> 6;
  int co = cg * 64 + lane;
  uint64_t wr[9 * W];
  const uint64_t* wg = wt + (long)co * (9 * W);
#pragma unroll
  for (int i = 0; i < 9 * W; i++) wr[i] = wg[i];
  __syncthreads();
  float alpha = cp[0];
  for (int pos = chunk * 4 + slot; pos < PH * PH; pos += POSCH * 4) {
    int py = pos / PH, px = pos % PH;
    int a00 = 0, a01 = 0, a10 = 0, a11 = 0;
#pragma unroll
    for (int cy = 0; cy < 4; cy++) {
      uint64_t row[4 * W];
      const uint64_t* rp = &sIn[((2 * py + cy) * IH + 2 * px) * W];
#pragma unroll
      for (int i = 0; i < 4 * W; i++) row[i] = rp[i];
#pragma unroll
      for (int dy = 0; dy < 2; dy++) {
        int ky = cy - dy;
        if (ky < 0 || ky > 2) continue;
#pragma unroll
        for (int dx = 0; dx < 2; dx++) {
          int a = 0;
#pragma unroll
          for (int kx = 0; kx < 3; kx++)
#pragma unroll
            for (int wd = 0; wd < W; wd++)
              a += __popcll(row[(dx + kx) * W + wd] ^ wr[(ky * 3 + kx) * W + wd]);
          if (dy == 0) { if (dx == 0) a00 += a; else a01 += a; }
          else         { if (dx == 0) a10 += a; else a11 += a; }
        }
      }
    }
    int pmin = min(min(a00, a01), min(a10, a11));
    int dot = 9 * 64 * W - 2 * pmin;
    float f = (float)dot;
    long idx = CL ? (((long)n * PH * PH + pos) * CO + co)
                  : (((long)n * CO + co) * PH * PH + pos);
    out[idx] = dot >= 0 ? f : alpha * f;
  }
}

// ---------------- binary fc ----------------

// transposed weights [wd][O]: wave-coalesced weight reads; nzc hoisted (r-const)
__global__ void fc_bin2(const uint64_t* __restrict__ xp, const uint64_t* __restrict__ wpT,
                        const float* __restrict__ cp, float* __restrict__ out,
                        int O, int Wf) {
  __shared__ uint64_t xs[288], xz[288];
  __shared__ int nztot;
  int r = blockIdx.y;
  if (threadIdx.x == 0) nztot = 0;
  __syncthreads();
  int lnz = 0;
  for (int i = threadIdx.x; i < Wf; i += blockDim.x) {
    uint64_t sv = xp[((long)r * Wf + i) * 2];
    uint64_t zv = xp[((long)r * Wf + i) * 2 + 1];
    xs[i] = sv; xz[i] = zv;
    lnz += __popcll(zv);
  }
  if (lnz) atomicAdd(&nztot, lnz);
  __syncthreads();
  int o = blockIdx.x * blockDim.x + threadIdx.x;
  int pc = 0;
  for (int wd = 0; wd < Wf; wd++)
    pc += __popcll((xs[wd] ^ wpT[(long)wd * O + o]) & xz[wd]);
  int dot = nztot - 2 * pc;
  float f = (float)dot;
  float alpha = cp[0];
  out[(long)r * O + o] = dot >= 0 ? f : alpha * f;
}

__global__ void fc_bin_scale(const uint64_t* __restrict__ xp, const uint64_t* __restrict__ wp,
                             const float* __restrict__ cp, const float* __restrict__ scale,
                             float* __restrict__ out, int R, int O, int Wf) {
  int i = blockIdx.x * blockDim.x + threadIdx.x;
  if (i >= R * O) return;
  int o = i % O, r = i / O;
  int pc = 0, nzc = 0;
  for (int wd = 0; wd < Wf; wd++) {
    uint64_t nz = xp[((long)r * Wf + wd) * 2 + 1];
    pc  += __popcll((xp[((long)r * Wf + wd) * 2] ^ wp[(long)o * Wf + wd]) & nz);
    nzc += __popcll(nz);
  }
  int dot = nzc - 2 * pc;
  float f = (float)dot;
  float alpha = cp[0];
  f = dot >= 0 ? f : alpha * f;
  out[i] = f * scale[0];
}

// ---------------- launch ----------------

extern "C" void kernel_launch(void* const* d_in, const int* in_sizes, int n_in,
                              void* d_out, int out_size, void* d_ws, size_t ws_size,
                              hipStream_t stream) {
  const float* x   = (const float*)d_in[0];
  const float* cg0 = (const float*)d_in[1];
  const float* cb0 = (const float*)d_in[2];
  const float* cw0 = (const float*)d_in[3];
  const float* cp0 = (const float*)d_in[4];
  const float* cg1 = (const float*)d_in[5];
  const float* cb1 = (const float*)d_in[6];
  const float* cw1 = (const float*)d_in[7];
  const float* cp1 = (const float*)d_in[8];
  const float* cg2 = (const float*)d_in[9];
  const float* cb2 = (const float*)d_in[10];
  const float* cw2 = (const float*)d_in[11];
  const float* cp2 = (const float*)d_in[12];
  const float* fg0 = (const float*)d_in[13];
  const float* fb0 = (const float*)d_in[14];
  const float* fw0 = (const float*)d_in[15];
  const float* fp0 = (const float*)d_in[16];
  const float* fg1 = (const float*)d_in[17];
  const float* fb1 = (const float*)d_in[18];
  const float* fw1 = (const float*)d_in[19];
  const float* fp1 = (const float*)d_in[20];
  const float* scl = (const float*)d_in[21];

  char* ws = (char*)d_ws;
  size_t off = 0;
  auto alloc = [&](size_t bytes) {
    size_t r = off;
    off += (bytes + 255) & ~(size_t)255;
    return r;
  };
  const int C0_OFF = 0, C1_OFF = 16, C2_OFF = 160, C3_OFF = 448, C4_OFF = 18944;
  const int NCH = 19968;

  double*   sums  = (double*)(ws + alloc(((size_t)NCH * 2 + 256) * sizeof(double)));
  int*      isums = (int*)(sums + (size_t)NCH * 2);
  double2*  stats = (double2*)(ws + alloc((size_t)NCH * sizeof(double2)));
  uint64_t* rows0 = (uint64_t*)(ws + alloc(128L * 3 * 64 * 8));
  uint32_t* wm1   = (uint32_t*)(ws + alloc(128L * 4));
  int8_t*   a1    = (int8_t*)(ws + alloc(128L * 961 * 128));      // int8 raw dots, channel-last
  uint64_t* s1p   = (uint64_t*)(ws + alloc(128L * 961 * 2 * 8));
  uint64_t* w1p   = (uint64_t*)(ws + alloc(256L * 9 * 2 * 8));
  float*    a2    = (float*)(ws + alloc(128L * 196 * 256 * 4));   // channel-last
  uint64_t* s2p   = (uint64_t*)(ws + alloc(128L * 196 * 4 * 8));
  uint64_t* w2p   = (uint64_t*)(ws + alloc(512L * 9 * 4 * 8));
  float*    a3    = (float*)(ws + alloc(128L * 512 * 36 * 4));    // channel-major (reshape order)
  uint64_t* s3p   = (uint64_t*)(ws + alloc(128L * 288 * 2 * 8));
  uint64_t* w3pT  = (uint64_t*)(ws + alloc(1024L * 288 * 8));     // TRANSPOSED [wd][O]
  float*    f1    = (float*)(ws + alloc(128L * 1024 * 4));
  uint64_t* s4p   = (uint64_t*)(ws + alloc(128L * 16 * 2 * 8));
  uint64_t* w4p   = (uint64_t*)(ws + alloc(10L * 16 * 8));

  const int B = 256;

  zero_d<<<dim3(157), B, 0, stream>>>(sums, NCH * 2 + 256);

  // ---- block 0: BN(x) -> sign-bits -> conv1(popcount) -> pool (raw int8 dots) ----
  reduce_plane<<<dim3(3, 128), B, 0, stream>>>(x, sums + 2 * C0_OFF, 3, 4096);
  finalize_stats<<<1, 64, 0, stream>>>(sums + 2 * C0_OFF, stats + C0_OFF, 3, 524288.0);
  pack_bits_c1<<<dim3(6144), B, 0, stream>>>(x, stats + C0_OFF, cg0, cb0, rows0);
  pack_wc1<<<1, 128, 0, stream>>>(cw0, wm1);
  conv1_pool3<<<dim3(16, 128), B, 0, stream>>>(rows0, wm1, a1);

  // ---- block 1: int-stat BN(a1) -> pack(prelu inline) -> conv2 -> pool -> prelu ----
  reduce_a1_i8<<<dim3(768), B, 0, stream>>>(a1, isums);
  finalize_i8<<<1, 128, 0, stream>>>(isums, cp0, stats + C1_OFF, 123008.0);
  pack_a1_i8<<<dim3(61504), B, 0, stream>>>(a1, stats + C1_OFF, cg1, cb1, cp0, s1p);
  pack_wconv2<<<dim3(256), B, 0, stream>>>(cw1, w1p, 128, 2);
  convp_slide<2, 31, 14, 4><<<dim3(16, 128), B, 0, stream>>>(s1p, w1p, cp1, a2, 256);

  // ---- block 2: BN(a2) -> pack -> conv3 -> pool -> prelu ----
  reduce_cl<<<dim3(4, 128), B, 0, stream>>>(a2, sums + 2 * C2_OFF, 256, 25088L);
  finalize_stats<<<1, 256, 0, stream>>>(sums + 2 * C2_OFF, stats + C2_OFF, 256, 25088.0);
  pack_cl<<<dim3(25088), B, 0, stream>>>(a2, stats + C2_OFF, cg2, cb2, s2p, 256, 100352L, 2);
  pack_wconv2<<<dim3(512), B, 0, stream>>>(cw2, w2p, 256, 4);
  convp_pool3<4, 14, 6, 2, false><<<dim3(16, 128), B, 0, stream>>>(s2p, w2p, cp2, a3, 512);

  // ---- fc 0: BN1d -> sign @ sign(W).T -> prelu ----
  reduce_cols2<<<dim3(72, 8), B, 0, stream>>>(a3, sums + 2 * C3_OFF, 128, 18432, 16);
  finalize_stats<<<dim3(72), B, 0, stream>>>(sums + 2 * C3_OFF, stats + C3_OFF, 18432, 128.0);
  pack_nz<<<dim3(9216), B, 0, stream>>>(a3, stats + C3_OFF, fg0, fb0, s3p, 128, 18432);
  pack_wfc2T<<<dim3(73728), B, 0, stream>>>(fw0, w3pT, 1024, 18432);
  fc_bin2<<<dim3(4, 128), B, 0, stream>>>(s3p, w3pT, fp0, f1, 1024, 288);

  // ---- fc 1: BN1d -> sign @ sign(W).T -> prelu -> scale ----
  reduce_cols2<<<dim3(4, 8), B, 0, stream>>>(f1, sums + 2 * C4_OFF, 128, 1024, 16);
  finalize_stats<<<dim3(4), B, 0, stream>>>(sums + 2 * C4_OFF, stats + C4_OFF, 1024, 128.0);
  pack_nz<<<dim3(512), B, 0, stream>>>(f1, stats + C4_OFF, fg1, fb1, s4p, 128, 1024);
  pack_wfc2<<<dim3(40), B, 0, stream>>>(fw1, w4p, 10, 1024);
  fc_bin_scale<<<dim3(5), B, 0, stream>>>(s4p, w4p, fp1, scl, (float*)d_out, 128, 10, 16);
}